// Round 1
// baseline (177.414 us; speedup 1.0000x reference)
//
#include <hip/hip_runtime.h>
#include <math.h>

constexpr int kN = 65536;
constexpr int kM = 64;
constexpr int kB = 16384;

// Broadcast a float from `lane` to all lanes via v_readlane (no DS traffic).
static __device__ __forceinline__ float bcastf(float v, int lane) {
    union { float f; int i; } u;
    u.f = v;
    u.i = __builtin_amdgcn_readlane(u.i, lane);
    return u.f;
}

__global__ __launch_bounds__(64) void gp_solve_kernel(
    const float* __restrict__ Uv,
    const float* __restrict__ Vv,
    const float* __restrict__ mean,
    const float* __restrict__ mean_post,
    const float* __restrict__ y,
    const int*   __restrict__ gidx,
    const int*   __restrict__ crow_u,
    const int*   __restrict__ crow_v,
    const float* __restrict__ noise,
    float*       __restrict__ partial)
{
    // pad 68: row stride 272B (16B-aligned for float4 reads), bank-balanced
    __shared__ __align__(16) float lds[64][68];

    const int lane = (int)threadIdx.x;   // p in [0,64)
    const int b    = (int)blockIdx.x;
    const int g    = gidx[b];

    // anchor row for this lane; valid <=> anc >= 0 (last L slots)
    const int  anc = g - 63 + lane;
    const bool vl  = (anc >= 0);

    int   rowbase = 0;
    float diag    = 1.0f;               // invalid rows are identity rows
    if (vl) {
        rowbase = crow_v[anc];
        diag    = Vv[rowbase];          // band row starts at its diagonal
    }
    const float invd = 1.0f / diag;

    const int L  = (g + 1 < 64) ? (g + 1) : 64;
    const int ub = crow_u[g];

    float uval = 0.0f, md = 0.0f;
    if (vl) {
        uval = Uv[ub + lane - (64 - L)];          // row g of U, last L slots
        md   = mean[anc] - mean_post[anc];
    }

    // ---- stage V_sub rows into LDS (coalesced 256B row loads) ----
    #pragma unroll 8
    for (int j = 0; j < 64; ++j) {
        const int rbj = __builtin_amdgcn_readlane(rowbase, j);  // uniform
        float val = 0.0f;
        if ((g - 63 + j) >= 0 && lane >= j)       // valid row & upper triangle
            val = Vv[rbj + (lane - j)];
        lds[j][lane] = val;
    }
    __syncthreads();

    // ---- transpose-read: lane j now holds row j in registers ----
    float v[64];
    #pragma unroll
    for (int k = 0; k < 16; ++k) {
        const float4 q = *reinterpret_cast<const float4*>(&lds[lane][4 * k]);
        v[4 * k + 0] = q.x;
        v[4 * k + 1] = q.y;
        v[4 * k + 2] = q.z;
        v[4 * k + 3] = q.w;
    }

    // ---- dual-RHS upper-triangular back-substitution (column sweep) ----
    float r_e = (lane == 63) ? 1.0f : 0.0f;   // e_{M-1}
    float r_u = uval;                         // U_sub
    float acc_e = 0.0f, acc_u = 0.0f;         // ||x||^2 accumulators (uniform)

    #pragma unroll
    for (int i = 63; i >= 0; --i) {
        const float t_e = r_e * invd;         // correct only on lane i
        const float t_u = r_u * invd;
        const float s_e = bcastf(t_e, i);     // x_i for RHS e
        const float s_u = bcastf(t_u, i);     // x_i for RHS u
        r_e = fmaf(-v[i], s_e, r_e);          // r[j] -= V[j][i] * x_i
        r_u = fmaf(-v[i], s_u, r_u);
        acc_e = fmaf(s_e, s_e, acc_e);
        acc_u = fmaf(s_u, s_u, acc_u);
    }

    // ---- dot(U_sub, md) via wave reduction ----
    float dot = uval * md;
    #pragma unroll
    for (int m = 1; m < 64; m <<= 1)
        dot += __shfl_xor(dot, m, 64);

    // diagonals for logDet come free from lane 63's registers
    const float ulast  = bcastf(uval, 63);    // U_values[crow_u[g+1]-1]
    const float vfirst = bcastf(diag, 63);    // V_values[crow_v[g]]

    if (lane == 0) {
        const float resid = y[g] - mean_post[g];
        const float inv2n = 0.5f / noise[0];
        const float C = logf(ulast) - logf(vfirst)
                      - 0.5f * dot * dot          // innerMean contribution
                      - 0.5f * acc_u              // innerCov contribution
                      - (resid * resid + acc_e) * inv2n;  // ell data terms
        partial[b] = C;
    }
}

__global__ __launch_bounds__(256) void gp_reduce_kernel(
    const float* __restrict__ partial,
    const float* __restrict__ noise,
    float*       __restrict__ out)
{
    __shared__ float ws[4];
    float a = 0.0f;
    for (int i = (int)threadIdx.x; i < kB; i += 256)
        a += partial[i];
    #pragma unroll
    for (int m = 1; m < 64; m <<= 1)
        a += __shfl_xor(a, m, 64);
    if ((threadIdx.x & 63u) == 0u)
        ws[threadIdx.x >> 6] = a;
    __syncthreads();
    if (threadIdx.x == 0) {
        float tot = ws[0] + ws[1] + ws[2] + ws[3];
        tot += -0.5f * (float)kB * logf(2.0f * 3.14159265358979323846f * noise[0]);
        out[0] = tot;
    }
}

extern "C" void kernel_launch(void* const* d_in, const int* in_sizes, int n_in,
                              void* d_out, int out_size, void* d_ws, size_t ws_size,
                              hipStream_t stream)
{
    const float* Uv        = (const float*)d_in[0];
    const float* Vv        = (const float*)d_in[1];
    const float* mean      = (const float*)d_in[2];
    const float* mean_post = (const float*)d_in[3];
    const float* y         = (const float*)d_in[4];
    const float* noise     = (const float*)d_in[5];
    const int*   gidx      = (const int*)d_in[6];
    const int*   crow_u    = (const int*)d_in[7];
    const int*   crow_v    = (const int*)d_in[8];
    float* partial = (float*)d_ws;   // kB floats = 64 KB scratch

    gp_solve_kernel<<<dim3(kB), dim3(64), 0, stream>>>(
        Uv, Vv, mean, mean_post, y, gidx, crow_u, crow_v, noise, partial);
    gp_reduce_kernel<<<dim3(1), dim3(256), 0, stream>>>(
        partial, noise, (float*)d_out);
}

// Round 2
// 81.862 us; speedup vs baseline: 2.1672x; 2.1672x over previous
//
#include <hip/hip_runtime.h>
#include <math.h>

constexpr int kN = 65536;
constexpr int kM = 64;
constexpr int kB = 16384;

// Broadcast a float from `lane` to all lanes via v_readlane (no DS traffic).
static __device__ __forceinline__ float bcastf(float v, int lane) {
    union { float f; int i; } u;
    u.f = v;
    u.i = __builtin_amdgcn_readlane(u.i, lane);
    return u.f;
}

__global__ __launch_bounds__(64) void gp_solve_kernel(
    const float* __restrict__ Uv,
    const float* __restrict__ Vv,
    const float* __restrict__ mean,
    const float* __restrict__ mean_post,
    const float* __restrict__ y,
    const int*   __restrict__ gidx,
    const int*   __restrict__ crow_u,
    const int*   __restrict__ crow_v,
    const float* __restrict__ noise,
    float*       __restrict__ partial)
{
    // pad 68: row stride 272B (16B-aligned for float4 reads), bank-balanced
    __shared__ __align__(16) float lds[64][68];

    const int lane = (int)threadIdx.x;   // p in [0,64)
    const int b    = (int)blockIdx.x;
    const int g    = gidx[b];

    // anchor row for this lane; valid <=> anc >= 0 (last L slots)
    const int  anc = g - 63 + lane;
    const bool vl  = (anc >= 0);

    int   rowbase = 0;
    float diag    = 1.0f;               // invalid rows are identity rows
    if (vl) rowbase = crow_v[anc];

    const int L  = (g + 1 < 64) ? (g + 1) : 64;
    const int ub = crow_u[g];

    // issue all small independent loads early (overlap with staging)
    float uval = 0.0f, md = 0.0f;
    if (vl) {
        uval = Uv[ub + lane - (64 - L)];          // row g of U, last L slots
        md   = mean[anc] - mean_post[anc];
    }
    if (vl) diag = Vv[rowbase];          // band row starts at its diagonal

    // ---- phase A: 64 fully-independent global loads into registers ----
    // stage[j] = V[j][lane]  (row j of V_sub, this lane's column)
    float stage[64];
    #pragma unroll
    for (int j = 0; j < 64; ++j) {
        const int rbj = __builtin_amdgcn_readlane(rowbase, j);  // uniform
        float val = 0.0f;
        if ((g - 63 + j) >= 0 && lane >= j)       // valid row & upper triangle
            val = Vv[rbj + (lane - j)];
        stage[j] = val;
    }

    // ---- phase B: drain registers to LDS (conflict-free writes) ----
    #pragma unroll
    for (int j = 0; j < 64; ++j)
        lds[j][lane] = stage[j];
    __syncthreads();

    const float invd = 1.0f / diag;

    // ---- transpose-read: lane j now holds row j in registers ----
    float v[64];
    #pragma unroll
    for (int k = 0; k < 16; ++k) {
        const float4 q = *reinterpret_cast<const float4*>(&lds[lane][4 * k]);
        v[4 * k + 0] = q.x;
        v[4 * k + 1] = q.y;
        v[4 * k + 2] = q.z;
        v[4 * k + 3] = q.w;
    }

    // ---- dual-RHS upper-triangular back-substitution (column sweep) ----
    float r_e = (lane == 63) ? 1.0f : 0.0f;   // e_{M-1}
    float r_u = uval;                         // U_sub
    float acc_e = 0.0f, acc_u = 0.0f;         // ||x||^2 accumulators (uniform)

    #pragma unroll
    for (int i = 63; i >= 0; --i) {
        const float t_e = r_e * invd;         // correct only on lane i
        const float t_u = r_u * invd;
        const float s_e = bcastf(t_e, i);     // x_i for RHS e
        const float s_u = bcastf(t_u, i);     // x_i for RHS u
        r_e = fmaf(-v[i], s_e, r_e);          // r[j] -= V[j][i] * x_i
        r_u = fmaf(-v[i], s_u, r_u);
        acc_e = fmaf(s_e, s_e, acc_e);
        acc_u = fmaf(s_u, s_u, acc_u);
    }

    // ---- dot(U_sub, md) via wave reduction ----
    float dot = uval * md;
    #pragma unroll
    for (int m = 1; m < 64; m <<= 1)
        dot += __shfl_xor(dot, m, 64);

    // diagonals for logDet come free from lane 63's registers
    const float ulast  = bcastf(uval, 63);    // U_values[crow_u[g+1]-1]
    const float vfirst = bcastf(diag, 63);    // V_values[crow_v[g]]

    if (lane == 0) {
        const float resid = y[g] - mean_post[g];
        const float inv2n = 0.5f / noise[0];
        const float C = logf(ulast) - logf(vfirst)
                      - 0.5f * dot * dot          // innerMean contribution
                      - 0.5f * acc_u              // innerCov contribution
                      - (resid * resid + acc_e) * inv2n;  // ell data terms
        partial[b] = C;
    }
}

__global__ __launch_bounds__(256) void gp_reduce_kernel(
    const float* __restrict__ partial,
    const float* __restrict__ noise,
    float*       __restrict__ out)
{
    __shared__ float ws[4];
    float a = 0.0f;
    for (int i = (int)threadIdx.x; i < kB; i += 256)
        a += partial[i];
    #pragma unroll
    for (int m = 1; m < 64; m <<= 1)
        a += __shfl_xor(a, m, 64);
    if ((threadIdx.x & 63u) == 0u)
        ws[threadIdx.x >> 6] = a;
    __syncthreads();
    if (threadIdx.x == 0) {
        float tot = ws[0] + ws[1] + ws[2] + ws[3];
        tot += -0.5f * (float)kB * logf(2.0f * 3.14159265358979323846f * noise[0]);
        out[0] = tot;
    }
}

extern "C" void kernel_launch(void* const* d_in, const int* in_sizes, int n_in,
                              void* d_out, int out_size, void* d_ws, size_t ws_size,
                              hipStream_t stream)
{
    const float* Uv        = (const float*)d_in[0];
    const float* Vv        = (const float*)d_in[1];
    const float* mean      = (const float*)d_in[2];
    const float* mean_post = (const float*)d_in[3];
    const float* y         = (const float*)d_in[4];
    const float* noise     = (const float*)d_in[5];
    const int*   gidx      = (const int*)d_in[6];
    const int*   crow_u    = (const int*)d_in[7];
    const int*   crow_v    = (const int*)d_in[8];
    float* partial = (float*)d_ws;   // kB floats = 64 KB scratch

    gp_solve_kernel<<<dim3(kB), dim3(64), 0, stream>>>(
        Uv, Vv, mean, mean_post, y, gidx, crow_u, crow_v, noise, partial);
    gp_reduce_kernel<<<dim3(1), dim3(256), 0, stream>>>(
        partial, noise, (float*)d_out);
}

// Round 3
// 52.983 us; speedup vs baseline: 3.3485x; 1.5451x over previous
//
#include <hip/hip_runtime.h>
#include <math.h>

constexpr int kN = 65536;
constexpr int kB = 16384;
constexpr int kWaves = 4;          // batch elements (waves) per block
constexpr int kTile = 2176;        // packed upper-triangular 64x64, rows padded to 4

// packed row offset: rows 4k..4k+3 have padded length 64-4k
static __device__ __forceinline__ constexpr int packed_off(int j) {
    const int q = j >> 2, r = j & 3;
    return 64 * j - 4 * (2 * q * (q - 1) + q * r);
}

static __device__ __forceinline__ float bcastf(float v, int lane) {
    union { float f; int i; } u;
    u.f = v;
    u.i = __builtin_amdgcn_readlane(u.i, lane);
    return u.f;
}

// async global->LDS, 4B per active lane; LDS dest = uniform base + lane*4
static __device__ __forceinline__ void gload_lds4(const float* g, float* l) {
    __builtin_amdgcn_global_load_lds(
        (const __attribute__((address_space(1))) void*)g,
        (__attribute__((address_space(3))) void*)l,
        4, 0, 0);
}

__global__ __launch_bounds__(64 * kWaves, 4) void gp_solve_kernel(
    const float* __restrict__ Uv,
    const float* __restrict__ Vv,
    const float* __restrict__ mean,
    const float* __restrict__ mean_post,
    const float* __restrict__ y,
    const int*   __restrict__ gidx,
    const int*   __restrict__ crow_u,
    const int*   __restrict__ crow_v,
    const float* __restrict__ noise,
    float*       __restrict__ partial)
{
    __shared__ __align__(16) float lds[kWaves][kTile];
    __shared__ float cred[kWaves];

    const int lane = (int)threadIdx.x & 63;
    const int wid  = (int)threadIdx.x >> 6;
    const int b    = (int)blockIdx.x * kWaves + wid;
    const int g    = gidx[b];
    float* myl = &lds[wid][0];

    // anchor row for this lane; valid <=> anc >= 0
    const int  anc = g - 63 + lane;
    const bool vl  = (anc >= 0);

    int rowbase = 0;
    if (vl) rowbase = crow_v[anc];

    const int L  = (g + 1 < 64) ? (g + 1) : 64;
    const int ub = crow_u[g];

    // small loads issued early; latency overlaps the staging below
    float uval = 0.0f, md = 0.0f, diag = 1.0f;
    if (vl) {
        uval = Uv[ub + lane - (64 - L)];      // row g of U, last L slots
        md   = mean[anc] - mean_post[anc];
        diag = Vv[rowbase];                   // band row starts at its diagonal
    }
    const float yg  = y[g];
    const float mpg = mean_post[g];
    const float invd = 1.0f / diag;

    // ---- stage packed upper triangle via global_load_lds ----
    // row j: elements d=0..63-j from Vv[rb_j + d] -> lds[off(j) + d]
    if (g >= 63) {                            // hot path: all rows valid
        #pragma unroll
        for (int j = 0; j < 64; ++j) {
            const int rbj = __builtin_amdgcn_readlane(rowbase, j);
            if (lane < 64 - j)
                gload_lds4(Vv + rbj + lane, myl + packed_off(j));
        }
    } else {                                  // rare: g < 63 -> some identity rows
        for (int j = 0; j < 64; ++j) {
            const int rbj = __builtin_amdgcn_readlane(rowbase, j);
            const int oj  = packed_off(j);
            if (lane < 64 - j) {
                if (g - 63 + j >= 0)
                    gload_lds4(Vv + rbj + lane, myl + oj);
                else
                    myl[oj + lane] = 0.0f;    // identity row: zeros off-diag
            }
        }
    }
    __syncthreads();   // drains vmcnt (global_load_lds) + lgkmcnt

    // ---- read row `lane` column-indexed: v[i] = V_sub[lane][i] ----
    // addr word = off(lane) - lane + i ; i<lane reads prior-row garbage,
    // which is HARMLESS: lane j's residual is consumed at step i=j, and
    // v[i<j] only updates r after that consumption.
    const int off_lane = packed_off(lane);
    const float* vrow = myl + (off_lane - lane);
    float v[64];
    #pragma unroll
    for (int i = 0; i < 64; ++i) v[i] = vrow[i];

    // ---- dual-RHS upper-triangular back-substitution (column sweep) ----
    float r_e = (lane == 63) ? 1.0f : 0.0f;   // e_{M-1}
    float r_u = uval;                         // U_sub
    float acc_e = 0.0f, acc_u = 0.0f;

    #pragma unroll
    for (int i = 63; i >= 0; --i) {
        const float t_e = r_e * invd;         // x_i valid on lane i
        const float t_u = r_u * invd;
        const float s_e = bcastf(t_e, i);
        const float s_u = bcastf(t_u, i);
        r_e = fmaf(-v[i], s_e, r_e);
        r_u = fmaf(-v[i], s_u, r_u);
        acc_e = fmaf(s_e, s_e, acc_e);
        acc_u = fmaf(s_u, s_u, acc_u);
    }

    // ---- dot(U_sub, md) via wave reduction ----
    float dot = uval * md;
    #pragma unroll
    for (int m = 1; m < 64; m <<= 1)
        dot += __shfl_xor(dot, m, 64);

    const float ulast  = bcastf(uval, 63);    // U_values[crow_u[g+1]-1]
    const float vfirst = bcastf(diag, 63);    // V_values[crow_v[g]]

    if (lane == 0) {
        const float resid = yg - mpg;
        const float inv2n = 0.5f / noise[0];
        cred[wid] = logf(ulast) - logf(vfirst)
                  - 0.5f * dot * dot
                  - 0.5f * acc_u
                  - (resid * resid + acc_e) * inv2n;
    }
    __syncthreads();
    if (threadIdx.x == 0)
        partial[blockIdx.x] = (cred[0] + cred[1]) + (cred[2] + cred[3]);
}

__global__ __launch_bounds__(1024) void gp_reduce_kernel(
    const float* __restrict__ partial,
    const float* __restrict__ noise,
    float*       __restrict__ out)
{
    __shared__ float ws[16];
    const int t = (int)threadIdx.x;
    const float4 p = reinterpret_cast<const float4*>(partial)[t];  // 4096 = 1024*4
    float a = (p.x + p.y) + (p.z + p.w);
    #pragma unroll
    for (int m = 1; m < 64; m <<= 1)
        a += __shfl_xor(a, m, 64);
    if ((t & 63) == 0) ws[t >> 6] = a;
    __syncthreads();
    if (t == 0) {
        float tot = 0.0f;
        #pragma unroll
        for (int k = 0; k < 16; ++k) tot += ws[k];
        tot += -0.5f * (float)kB * logf(2.0f * 3.14159265358979323846f * noise[0]);
        out[0] = tot;
    }
}

extern "C" void kernel_launch(void* const* d_in, const int* in_sizes, int n_in,
                              void* d_out, int out_size, void* d_ws, size_t ws_size,
                              hipStream_t stream)
{
    const float* Uv        = (const float*)d_in[0];
    const float* Vv        = (const float*)d_in[1];
    const float* mean      = (const float*)d_in[2];
    const float* mean_post = (const float*)d_in[3];
    const float* y         = (const float*)d_in[4];
    const float* noise     = (const float*)d_in[5];
    const int*   gidx      = (const int*)d_in[6];
    const int*   crow_u    = (const int*)d_in[7];
    const int*   crow_v    = (const int*)d_in[8];
    float* partial = (float*)d_ws;   // kB/kWaves = 4096 floats

    gp_solve_kernel<<<dim3(kB / kWaves), dim3(64 * kWaves), 0, stream>>>(
        Uv, Vv, mean, mean_post, y, gidx, crow_u, crow_v, noise, partial);
    gp_reduce_kernel<<<dim3(1), dim3(1024), 0, stream>>>(
        partial, noise, (float*)d_out);
}

// Round 4
// 43.599 us; speedup vs baseline: 4.0692x; 1.2152x over previous
//
#include <hip/hip_runtime.h>
#include <math.h>

constexpr int kN = 65536;
constexpr int kB = 16384;
constexpr int kWaves = 4;          // batch elements (waves) per block
constexpr int kTileW = 3072;       // words/wave: 32 rows x 64 + 32 rows x 32

static __device__ __forceinline__ float bcastf(float v, int lane) {
    union { float f; int i; } u;
    u.f = v;
    u.i = __builtin_amdgcn_readlane(u.i, lane);
    return u.f;
}

// async global->LDS; LDS dest = wave-uniform base + lane*size
static __device__ __forceinline__ void gload_lds16(const float* g, float* l) {
    __builtin_amdgcn_global_load_lds(
        (const __attribute__((address_space(1))) void*)g,
        (__attribute__((address_space(3))) void*)l, 16, 0, 0);
}
static __device__ __forceinline__ void gload_lds4(const float* g, float* l) {
    __builtin_amdgcn_global_load_lds(
        (const __attribute__((address_space(1))) void*)g,
        (__attribute__((address_space(3))) void*)l, 4, 0, 0);
}

__global__ __launch_bounds__(64 * kWaves) void gp_solve_kernel(
    const float* __restrict__ Uv,
    const float* __restrict__ Vv,
    const float* __restrict__ mean,
    const float* __restrict__ mean_post,
    const float* __restrict__ y,
    const int*   __restrict__ gidx,
    const int*   __restrict__ crow_u,
    const int*   __restrict__ crow_v,
    const float* __restrict__ noise,
    float*       __restrict__ partial)
{
    // half-packed tile: rows j<32 full 64 words at 64*j;
    // rows j>=32 first 32 words (the needed triangle) at 1024+32*j.
    __shared__ __align__(16) float lds[kWaves][kTileW];
    __shared__ float cred[kWaves];

    const int lane = (int)threadIdx.x & 63;
    const int wid  = (int)threadIdx.x >> 6;
    const int b    = (int)blockIdx.x * kWaves + wid;
    const int g    = gidx[b];
    float* myl = &lds[wid][0];

    const int  anc = g - 63 + lane;            // this lane's row index
    const bool vl  = (anc >= 0);
    const bool hot = (g >= 63) && (g <= kN - 64);   // fully regular band region

    // U row: crow_u[g] = 2016 + 64*(g-63) for all g>=63 (U rows never shorten)
    const int L  = (g + 1 < 64) ? (g + 1) : 64;
    const int ub = (g >= 63) ? (2016 + 64 * (g - 63)) : crow_u[g];

    float uval = 0.0f, md = 0.0f;
    if (vl) {
        uval = Uv[ub + lane - (64 - L)];       // row g of U, last L slots
        md   = mean[anc] - mean_post[anc];
    }
    const float yg  = y[g];
    const float mpg = mean_post[g];

    if (hot) {
        // crow_v[a] = 64*a here: tile rows are one contiguous 16KB block.
        // Region A: rows 0..31 full width (2048 words, 8 x 1KB loads)
        const float* srcA = Vv + 64 * (g - 63) + 4 * lane;
        #pragma unroll
        for (int k = 0; k < 8; ++k)
            gload_lds16(srcA + 256 * k, myl + 256 * k);
        // Region B: rows 32..63, first 32 words each (1024 words, 4 x 1KB)
        // word w = 256k+4*lane -> local row jj = w>>5, col d = w&31
        const int rowoff = 64 * (lane >> 3) + 4 * (lane & 7);
        const float* srcB = Vv + 64 * (g - 31) + rowoff;
        #pragma unroll
        for (int k = 0; k < 4; ++k)
            gload_lds16(srcB + 512 * k, myl + 2048 + 256 * k);
    } else {
        // rare (~32/16384 waves): g<63 (identity rows) or band tail (short rows)
        int rowbase = 0;
        if (vl) rowbase = crow_v[anc];
        for (int j = 0; j < 64; ++j) {
            const int rbj = __builtin_amdgcn_readlane(rowbase, j);
            const int dst = (j < 32) ? 64 * j : (1024 + 32 * j);
            if (lane < 64 - j) {               // only the needed triangle words
                if (g - 63 + j >= 0)
                    gload_lds4(Vv + rbj + lane, myl + dst);
                else
                    myl[dst + lane] = 0.0f;    // identity row: zeros (diag fixed below)
            }
        }
    }
    __syncthreads();   // drains global_load_lds (vmcnt) + lgkmcnt

    // lane j's row starts at rowstart; consumed words are 0..63-j.
    const int rowstart = (lane < 32) ? (64 * lane) : (1024 + 32 * lane);
    const float d0 = myl[rowstart];
    const float diag = vl ? d0 : 1.0f;         // identity rows: unit diagonal
    const float invd = 1.0f / diag;

    // v[i] = V_sub[lane][i] for i>=lane; i<lane reads garbage (provably unused
    // before consumption of this lane's residual at step i=lane).
    const float* vrowm = myl + (rowstart - lane);
    float v[64];
    #pragma unroll
    for (int i = 0; i < 64; ++i) v[i] = vrowm[i];

    // ---- dual-RHS upper-triangular back-substitution (column sweep) ----
    float r_e = (lane == 63) ? 1.0f : 0.0f;    // e_{M-1}
    float r_u = uval;                          // U_sub
    float acc_e = 0.0f, acc_u = 0.0f;

    #pragma unroll
    for (int i = 63; i >= 0; --i) {
        const float t_e = r_e * invd;          // x_i valid on lane i
        const float t_u = r_u * invd;
        const float s_e = bcastf(t_e, i);
        const float s_u = bcastf(t_u, i);
        r_e = fmaf(-v[i], s_e, r_e);
        r_u = fmaf(-v[i], s_u, r_u);
        acc_e = fmaf(s_e, s_e, acc_e);
        acc_u = fmaf(s_u, s_u, acc_u);
    }

    // ---- dot(U_sub, md) via wave reduction ----
    float dot = uval * md;
    #pragma unroll
    for (int m = 1; m < 64; m <<= 1)
        dot += __shfl_xor(dot, m, 64);

    const float ulast  = bcastf(uval, 63);     // U_values[crow_u[g+1]-1]
    const float vfirst = bcastf(diag, 63);     // V_values[crow_v[g]]

    if (lane == 0) {
        const float resid = yg - mpg;
        const float inv2n = 0.5f / noise[0];
        cred[wid] = logf(ulast) - logf(vfirst)
                  - 0.5f * dot * dot
                  - 0.5f * acc_u
                  - (resid * resid + acc_e) * inv2n;
    }
    __syncthreads();
    if (threadIdx.x == 0)
        partial[blockIdx.x] = (cred[0] + cred[1]) + (cred[2] + cred[3]);
}

__global__ __launch_bounds__(1024) void gp_reduce_kernel(
    const float* __restrict__ partial,
    const float* __restrict__ noise,
    float*       __restrict__ out)
{
    __shared__ float ws[16];
    const int t = (int)threadIdx.x;
    const float4 p = reinterpret_cast<const float4*>(partial)[t];  // 4096 = 1024*4
    float a = (p.x + p.y) + (p.z + p.w);
    #pragma unroll
    for (int m = 1; m < 64; m <<= 1)
        a += __shfl_xor(a, m, 64);
    if ((t & 63) == 0) ws[t >> 6] = a;
    __syncthreads();
    if (t == 0) {
        float tot = 0.0f;
        #pragma unroll
        for (int k = 0; k < 16; ++k) tot += ws[k];
        tot += -0.5f * (float)kB * logf(2.0f * 3.14159265358979323846f * noise[0]);
        out[0] = tot;
    }
}

extern "C" void kernel_launch(void* const* d_in, const int* in_sizes, int n_in,
                              void* d_out, int out_size, void* d_ws, size_t ws_size,
                              hipStream_t stream)
{
    const float* Uv        = (const float*)d_in[0];
    const float* Vv        = (const float*)d_in[1];
    const float* mean      = (const float*)d_in[2];
    const float* mean_post = (const float*)d_in[3];
    const float* y         = (const float*)d_in[4];
    const float* noise     = (const float*)d_in[5];
    const int*   gidx      = (const int*)d_in[6];
    const int*   crow_u    = (const int*)d_in[7];
    const int*   crow_v    = (const int*)d_in[8];
    float* partial = (float*)d_ws;   // kB/kWaves = 4096 floats

    gp_solve_kernel<<<dim3(kB / kWaves), dim3(64 * kWaves), 0, stream>>>(
        Uv, Vv, mean, mean_post, y, gidx, crow_u, crow_v, noise, partial);
    gp_reduce_kernel<<<dim3(1), dim3(1024), 0, stream>>>(
        partial, noise, (float*)d_out);
}

// Round 5
// 38.631 us; speedup vs baseline: 4.5925x; 1.1286x over previous
//
#include <hip/hip_runtime.h>
#include <math.h>

constexpr int kN = 65536;
constexpr int kB = 16384;
constexpr int kTileW = 2560;   // tiered packed triangle: 16*64+16*48+16*32+16*16 words

static __device__ __forceinline__ float bcastf(float v, int lane) {
    union { float f; int i; } u;
    u.f = v;
    u.i = __builtin_amdgcn_readlane(u.i, lane);
    return u.f;
}

// async global->LDS; LDS dest = wave-uniform base + lane*size (active lanes only)
static __device__ __forceinline__ void gload_lds16(const float* g, float* l) {
    __builtin_amdgcn_global_load_lds(
        (const __attribute__((address_space(1))) void*)g,
        (__attribute__((address_space(3))) void*)l, 16, 0, 0);
}
static __device__ __forceinline__ void gload_lds4(const float* g, float* l) {
    __builtin_amdgcn_global_load_lds(
        (const __attribute__((address_space(1))) void*)g,
        (__attribute__((address_space(3))) void*)l, 4, 0, 0);
}

// tier layout: row j (tier t=j>>4, width w=64-16t) starts at
// off(t) + w*(j-16t), off(t) = 1024t - 128t(t-1)
static __device__ __forceinline__ int row_start(int j) {
    const int t = j >> 4;
    return 1024 * t - 128 * t * (t - 1) + (64 - 16 * t) * (j - 16 * t);
}

__global__ __launch_bounds__(64) void gp_solve_kernel(
    const float* __restrict__ Uv,
    const float* __restrict__ Vv,
    const float* __restrict__ mean,
    const float* __restrict__ mean_post,
    const float* __restrict__ y,
    const int*   __restrict__ gidx,
    const int*   __restrict__ crow_u,
    const int*   __restrict__ crow_v,
    const float* __restrict__ noise,
    float*       __restrict__ partial)
{
    __shared__ __align__(16) float myl[kTileW];

    const int lane = (int)threadIdx.x;          // 0..63
    const int b    = (int)blockIdx.x;
    const int g    = gidx[b];

    const int  anc = g - 63 + lane;             // this lane's row index
    const bool vl  = (anc >= 0);
    // hot: all 64 tile rows have crow_v[a] = 64a (regular band region)
    const bool hot = (g >= 63) && (g <= kN - 63);

    // U row: crow_u[g] = 2016 + 64*(g-63) for g>=63 (U rows never shorten)
    const int L  = (g + 1 < 64) ? (g + 1) : 64;
    const int ub = (g >= 63) ? (2016 + 64 * (g - 63)) : crow_u[g];

    float uval = 0.0f, md = 0.0f;
    if (vl) {
        uval = Uv[ub + lane - (64 - L)];        // row g of U, last L slots
        md   = mean[anc] - mean_post[anc];
    }
    const float yg  = y[g];
    const float mpg = mean_post[g];

    if (hot) {
        const float* base = Vv + 64 * (g - 63);  // contiguous 16KB row block
        // tier0: rows 0..15 full width (1024 words @ 0)
        {
            const float* src = base + 4 * lane;
            #pragma unroll
            for (int k = 0; k < 4; ++k)
                gload_lds16(src + 256 * k, myl + 256 * k);
        }
        // tier1: rows 16..31, width 48 (768 words @ 1024)
        #pragma unroll
        for (int k = 0; k < 3; ++k) {
            const int w   = 256 * k + 4 * lane;
            const int jj  = ((w >> 4) * 171) >> 9;   // exact (w/16)/3 for w<768
            const int col = w - 48 * jj;
            gload_lds16(base + 64 * (16 + jj) + col, myl + 1024 + 256 * k);
        }
        // tier2: rows 32..47, width 32 (512 words @ 1792)
        #pragma unroll
        for (int k = 0; k < 2; ++k) {
            const int w = 256 * k + 4 * lane;
            gload_lds16(base + 64 * (32 + (w >> 5)) + (w & 31), myl + 1792 + 256 * k);
        }
        // tier3: rows 48..63, width 16 (256 words @ 2304)
        {
            const int w = 4 * lane;
            gload_lds16(base + 64 * (48 + (w >> 4)) + (w & 15), myl + 2304);
        }
    } else {
        // rare (~32/16384 waves): g<63 (identity rows) or band tail (crow_v irregular)
        int rowbase = 0;
        if (vl) rowbase = crow_v[anc];
        for (int j = 0; j < 64; ++j) {
            union { float f; int i; } rb; rb.i = __builtin_amdgcn_readlane(rowbase, j);
            const int dst = row_start(j);
            if (lane < 64 - j) {                 // exactly the consumed words
                if (g - 63 + j >= 0)
                    gload_lds4(Vv + rb.i + lane, myl + dst);
                else
                    myl[dst + lane] = 0.0f;      // identity row: zero off-diag
            }
        }
    }
    // per-wave drain of global_load_lds (vmcnt) and ds_write (lgkm); the
    // "memory" clobber orders the ds_reads below behind this wait.
    asm volatile("s_waitcnt vmcnt(0) lgkmcnt(0)" ::: "memory");

    const int rs = row_start(lane);
    const float d0   = myl[rs];
    const float diag = vl ? d0 : 1.0f;           // identity rows: unit diagonal
    const float invd = 1.0f / diag;

    // v[i] = V_sub[lane][i] for i>=lane; i<lane reads prior rows' garbage,
    // provably unused before this lane's residual is consumed at step i=lane.
    const float* vrow = myl + (rs - lane);
    float v[64];
    #pragma unroll
    for (int i = 0; i < 64; ++i) v[i] = vrow[i];

    // ---- dual-RHS upper-triangular back-substitution (column sweep) ----
    float r_e = (lane == 63) ? 1.0f : 0.0f;      // e_{M-1}
    float r_u = uval;                            // U_sub
    float acc_e = 0.0f, acc_u = 0.0f;

    #pragma unroll
    for (int i = 63; i >= 0; --i) {
        const float t_e = r_e * invd;            // x_i valid on lane i
        const float t_u = r_u * invd;
        const float s_e = bcastf(t_e, i);
        const float s_u = bcastf(t_u, i);
        r_e = fmaf(-v[i], s_e, r_e);
        r_u = fmaf(-v[i], s_u, r_u);
        acc_e = fmaf(s_e, s_e, acc_e);
        acc_u = fmaf(s_u, s_u, acc_u);
    }

    // ---- dot(U_sub, md) via wave reduction ----
    float dot = uval * md;
    #pragma unroll
    for (int m = 1; m < 64; m <<= 1)
        dot += __shfl_xor(dot, m, 64);

    const float ulast  = bcastf(uval, 63);       // U_values[crow_u[g+1]-1]
    const float vfirst = bcastf(diag, 63);       // V_values[crow_v[g]]

    if (lane == 0) {
        const float resid = yg - mpg;
        const float inv2n = 0.5f / noise[0];
        partial[b] = logf(ulast) - logf(vfirst)
                   - 0.5f * dot * dot
                   - 0.5f * acc_u
                   - (resid * resid + acc_e) * inv2n;
    }
}

__global__ __launch_bounds__(1024) void gp_reduce_kernel(
    const float* __restrict__ partial,
    const float* __restrict__ noise,
    float*       __restrict__ out)
{
    __shared__ float ws[16];
    const int t = (int)threadIdx.x;
    float a = 0.0f;
    #pragma unroll
    for (int k = 0; k < 4; ++k) {                // 4096 float4 = 16384 floats
        const float4 p = reinterpret_cast<const float4*>(partial)[t + 1024 * k];
        a += (p.x + p.y) + (p.z + p.w);
    }
    #pragma unroll
    for (int m = 1; m < 64; m <<= 1)
        a += __shfl_xor(a, m, 64);
    if ((t & 63) == 0) ws[t >> 6] = a;
    __syncthreads();
    if (t == 0) {
        float tot = 0.0f;
        #pragma unroll
        for (int k = 0; k < 16; ++k) tot += ws[k];
        tot += -0.5f * (float)kB * logf(2.0f * 3.14159265358979323846f * noise[0]);
        out[0] = tot;
    }
}

extern "C" void kernel_launch(void* const* d_in, const int* in_sizes, int n_in,
                              void* d_out, int out_size, void* d_ws, size_t ws_size,
                              hipStream_t stream)
{
    const float* Uv        = (const float*)d_in[0];
    const float* Vv        = (const float*)d_in[1];
    const float* mean      = (const float*)d_in[2];
    const float* mean_post = (const float*)d_in[3];
    const float* y         = (const float*)d_in[4];
    const float* noise     = (const float*)d_in[5];
    const int*   gidx      = (const int*)d_in[6];
    const int*   crow_u    = (const int*)d_in[7];
    const int*   crow_v    = (const int*)d_in[8];
    float* partial = (float*)d_ws;   // kB floats = 64 KB scratch

    gp_solve_kernel<<<dim3(kB), dim3(64), 0, stream>>>(
        Uv, Vv, mean, mean_post, y, gidx, crow_u, crow_v, noise, partial);
    gp_reduce_kernel<<<dim3(1), dim3(1024), 0, stream>>>(
        partial, noise, (float*)d_out);
}